// Round 4
// baseline (533.884 us; speedup 1.0000x reference)
//
#include <hip/hip_runtime.h>

#define Bn 32
#define Nn 24564
#define MAXB 200
#define TSEL 8192
#define NBIN 2048

typedef unsigned long long u64;
typedef unsigned int u32;

// -------- accurate double exp (rel err ~6e-15) -- proven bit-stable in R2/R3
__device__ inline double fast_exp_d(double x) {
  const double LOG2E = 1.4426950408889634074;
  const double LN2   = 0.69314718055994530942;
  double t = x * LOG2E;
  double fi = floor(t + 0.5);
  double f = (t - fi) * LN2;
  double p = 2.505210838544172e-8;
  p = p * f + 2.755731922398589e-7;
  p = p * f + 2.7557319223985893e-6;
  p = p * f + 2.48015873015873e-5;
  p = p * f + 1.984126984126984e-4;
  p = p * f + 1.3888888888888889e-3;
  p = p * f + 8.333333333333333e-3;
  p = p * f + 4.1666666666666664e-2;
  p = p * f + 1.6666666666666666e-1;
  p = p * f + 0.5;
  p = p * f + 1.0;
  p = p * f + 1.0;
  long long e = (long long)fi;
  return p * __longlong_as_double((e + 1023LL) << 52);
}

__device__ inline double clip01(double v) {
  return v < 0.0 ? 0.0 : (v > 1.0 ? 1.0 : v);
}

// ============================================================
// K1: fast f32 scoring -> per-anchor preselection bin + global histogram
// bin_a ascending == score descending. invalid -> 0xFFFFFFFF.
// ============================================================
__global__ __launch_bounds__(256) void k_score(const float* __restrict__ logits,
                                               u32* __restrict__ binA,
                                               int* __restrict__ hist) {
  __shared__ float lds[64 * 85];
  const int tid = threadIdx.x;
  const int bx = blockIdx.x;
  const int b = bx / 384;
  const int n0 = (bx % 384) << 6;
  int cnt = Nn - n0;
  cnt = cnt > 64 ? 64 : cnt;               // 64 or 52
  const int nf4 = (cnt * 85) >> 2;         // divisible by 4 for 64/52
  const float4* src = reinterpret_cast<const float4*>(logits + ((size_t)b * Nn + n0) * 85);
  float4* dst = reinterpret_cast<float4*>(lds);
  for (int i = tid; i < nf4; i += 256) dst[i] = src[i];
  __syncthreads();

  const int g = tid >> 2;
  const int s = tid & 3;
  if (g < cnt) {
    const float* row = lds + g * 85;
    float mx = -1e30f; int ai = 1000;
    for (int c = s; c < 81; c += 4) {
      float v = row[4 + c];
      if (v > mx) { mx = v; ai = c; }
    }
    #pragma unroll
    for (int d = 1; d <= 2; d <<= 1) {
      float om = __shfl_xor(mx, d);
      int oi = __shfl_xor(ai, d);
      if (om > mx || (om == mx && oi < ai)) { mx = om; ai = oi; }
    }
    float sum = 0.f;
    for (int c = s; c < 81; c += 4) sum += __expf(row[4 + c] - mx);
    sum += __shfl_xor(sum, 1);
    sum += __shfl_xor(sum, 2);

    if (s == 0) {
      float sc = 1.0f / sum;
      u32 out = 0xFFFFFFFFu;
      if (ai != 0 && sc >= 0.00985f) {     // margin below exact 0.01; K3 rechecks exactly
        u32 sb = __float_as_uint(sc);
        int e3 = (int)(sb >> 23) - 119;    // 1..7 for sc in [0.00985, 1)
        int bin_desc = (e3 << 8) | (int)((sb >> 15) & 0xFF);
        int bin_a = 2047 - bin_desc;
        bin_a = bin_a < 0 ? 0 : bin_a;
        out = (u32)bin_a;
        atomicAdd(&hist[b * NBIN + bin_a], 1);
      }
      binA[(size_t)b * Nn + n0 + g] = out;
    }
  }
}

// ============================================================
// K2a: per-image cutoff bin C = largest bin with inclusive cumsum <= TSEL
// ============================================================
__global__ __launch_bounds__(256) void k_cutoff(const int* __restrict__ hist,
                                                int* __restrict__ Cg) {
  __shared__ int part[256];
  __shared__ int gincl[64];
  __shared__ int sC;
  const int b = blockIdx.x;
  const int tid = threadIdx.x;
  int h[8];
  int ps = 0;
  #pragma unroll
  for (int q = 0; q < 8; ++q) { h[q] = hist[b * NBIN + tid * 8 + q]; ps += h[q]; }
  part[tid] = ps;
  if (tid == 0) sC = -1;
  __syncthreads();
  if (tid < 64) {
    int s4 = part[tid * 4] + part[tid * 4 + 1] + part[tid * 4 + 2] + part[tid * 4 + 3];
    int run = s4;
    for (int d = 1; d < 64; d <<= 1) {
      int v = __shfl_up(run, d);
      if (tid >= d) run += v;
    }
    gincl[tid] = run;   // inclusive sum over groups of 4 threads
  }
  __syncthreads();
  int base = (tid >> 2) ? gincl[(tid >> 2) - 1] : 0;
  for (int q = (tid & ~3); q < tid; ++q) base += part[q];
  int run = base, localC = -1;
  #pragma unroll
  for (int q = 0; q < 8; ++q) {
    run += h[q];
    if (run <= TSEL) localC = tid * 8 + q;
  }
  if (localC >= 0) atomicMax(&sC, localC);
  __syncthreads();
  if (tid == 0) Cg[b] = sC;
}

// ============================================================
// K2b: grid-wide ballot compaction of anchors with bin <= C into clist
// ============================================================
__global__ __launch_bounds__(256) void k_compact(const u32* __restrict__ binA,
                                                 const int* __restrict__ Cg,
                                                 int* __restrict__ cntG,
                                                 int* __restrict__ clist) {
  const int tid = threadIdx.x;
  const int bx = blockIdx.x;
  const int b = bx / 96;
  const int i = ((bx % 96) << 8) + tid;
  const u32 C = (u32)Cg[b];
  bool pred = false;
  if (i < Nn) pred = (binA[(size_t)b * Nn + i] <= C);
  u64 m = __ballot(pred);
  int lane = tid & 63;
  int base = 0;
  if (lane == 0 && m) base = atomicAdd(&cntG[b], (int)__popcll(m));
  base = __shfl(base, 0);
  if (pred) {
    int off = (int)__popcll(m & ((1ULL << lane) - 1ULL));
    int p = base + off;
    if (p < TSEL) clist[b * TSEL + p] = i;
  }
}

// ============================================================
// K3: exact f64 rescore of <=8192 candidates/image (full-chip parallel).
// Bit-identical reduction order to the R2/R3-proven kernel.
// ============================================================
__global__ __launch_bounds__(512) void k_rescore(const float* __restrict__ logits,
                                                 const float* __restrict__ anchors,
                                                 const int* __restrict__ clist,
                                                 const int* __restrict__ cntG,
                                                 double* __restrict__ boxesd,
                                                 int* __restrict__ clsd,
                                                 u64* __restrict__ ekeys) {
  const int tid = threadIdx.x;
  const int bx = blockIdx.x;
  const int b = bx >> 6;
  const int slot = ((bx & 63) << 7) + (tid >> 2);
  const int s = tid & 3;
  int cnt = cntG[b];
  cnt = cnt > TSEL ? TSEL : cnt;

  u64 K = ~0ULL;
  if (slot < cnt) {
    const int n = clist[b * TSEL + slot];
    const float* row = logits + ((size_t)b * Nn + n) * 85;
    float rv[21];
    int nc = 0;
    float mx = -1e30f; int ai = 1000;
    for (int c = s; c < 81; c += 4) {
      float v = row[4 + c];
      rv[nc++] = v;
      if (v > mx) { mx = v; ai = c; }
    }
    #pragma unroll
    for (int d = 1; d <= 2; d <<= 1) {
      float om = __shfl_xor(mx, d);
      int oi = __shfl_xor(ai, d);
      if (om > mx || (om == mx && oi < ai)) { mx = om; ai = oi; }
    }
    double sum = 0.0;
    for (int q = 0; q < nc; ++q) sum += fast_exp_d((double)rv[q] - (double)mx);
    sum += __shfl_xor(sum, 1);
    sum += __shfl_xor(sum, 2);

    if (s == 0) {
      double score = 1.0 / sum;
      if (ai != 0 && score >= 0.01) {
        float4 a4 = reinterpret_cast<const float4*>(anchors)[n];
        double ax1 = a4.x, ay1 = a4.y, ax2 = a4.z, ay2 = a4.w;
        double cx = (ax2 + ax1) * 0.5, cy = (ay2 + ay1) * 0.5;
        double ww = ax2 - ax1, hh = ay2 - ay1;
        double ctrx = (double)row[0] * ww + cx;
        double ctry = (double)row[1] * hh + cy;
        double szx = fast_exp_d((double)row[2]) * ww;
        double szy = fast_exp_d((double)row[3]) * hh;
        double* bp = boxesd + (size_t)(b * Nn + n) * 4;
        bp[0] = clip01(ctrx - szx * 0.5);
        bp[1] = clip01(ctry - szy * 0.5);
        bp[2] = clip01(ctrx + szx * 0.5);
        bp[3] = clip01(ctry + szy * 0.5);
        clsd[b * Nn + n] = ai;
        u64 sb = (u64)__double_as_longlong(score);
        u64 e4 = (sb >> 52) - 1015ULL;
        u64 mant45 = (sb & ((1ULL << 52) - 1)) >> 7;
        u64 flip = (~((e4 << 45) | mant45)) & ((1ULL << 49) - 1);
        K = (flip << 15) | (u64)n;
      }
    }
  }
  if (s == 0) ekeys[b * TSEL + slot] = K;
}

// ============================================================
// K4: LDS bitonic sort of 8192 exact keys + greedy NMS + outputs
// ============================================================
__global__ __launch_bounds__(1024) void k_nms(const u64* __restrict__ ekeys,
                                              const double* __restrict__ boxesd,
                                              const int* __restrict__ clsd,
                                              float* __restrict__ out) {
  __shared__ u64 sel[TSEL];               // 64 KB
  __shared__ double selBox[MAXB][4];
  __shared__ double selArea[MAXB];
  __shared__ float selScore[MAXB];
  __shared__ int selIdx[MAXB];
  __shared__ int sS;
  const int b = blockIdx.x;
  const int tid = threadIdx.x;

  for (int i = tid; i < TSEL; i += 1024) sel[i] = ekeys[b * TSEL + i];
  __syncthreads();

  for (int k = 2; k <= TSEL; k <<= 1) {
    for (int j = k >> 1; j >= 1; j >>= 1) {
      for (int p = tid; p < (TSEL / 2); p += 1024) {
        int l = ((p & ~(j - 1)) << 1) | (p & (j - 1));
        int r = l | j;
        bool up = ((l & k) == 0);
        u64 a = sel[l], bb = sel[r];
        if ((a > bb) == up) { sel[l] = bb; sel[r] = a; }
      }
      __syncthreads();
    }
  }

  if (tid < 64) {
    const int lane = tid;
    const double THR = 0.45;
    int S = 0, pos = 0;
    while (S < MAXB && pos < TSEL) {
      u64 K = sel[pos + lane];
      bool valid = (K != ~0ULL);
      if (!__any(valid)) break;
      int idx = (int)(K & 0x7FFF);
      double bx1 = 0, by1 = 0, bx2 = 0, by2 = 0, area = 0;
      float sc = 0.f;
      if (valid) {
        const double* bp = boxesd + (size_t)(b * Nn + idx) * 4;
        bx1 = bp[0]; by1 = bp[1]; bx2 = bp[2]; by2 = bp[3];
        area = (bx2 - bx1) * (by2 - by1);
        u64 key49 = (~(K >> 15)) & ((1ULL << 49) - 1);
        u64 e = (key49 >> 45) + 1015ULL;
        u64 mant = (key49 & ((1ULL << 45) - 1)) << 7;
        sc = (float)__longlong_as_double((long long)((e << 52) | mant));
      }
      bool alive = valid;
      for (int k = 0; k < S; ++k) {
        double ltx = fmax(selBox[k][0], bx1), lty = fmax(selBox[k][1], by1);
        double rbx = fmin(selBox[k][2], bx2), rby = fmin(selBox[k][3], by2);
        double w = rbx - ltx; w = w < 0 ? 0 : w;
        double h = rby - lty; h = h < 0 ? 0 : h;
        double inter = w * h;
        double denom = selArea[k] + area - inter + 1e-9;
        if (inter > THR * denom) alive = false;
        if ((k & 7) == 7 && !__any(alive)) break;
      }
      u64 m = __ballot(alive);
      while (m != 0 && S < MAXB) {
        int j = __ffsll((unsigned long long)m) - 1;
        double jx1 = __shfl(bx1, j), jy1 = __shfl(by1, j);
        double jx2 = __shfl(bx2, j), jy2 = __shfl(by2, j);
        double jar = __shfl(area, j);
        float jsc = __shfl(sc, j);
        int jidx = __shfl(idx, j);
        if (lane == 0) {
          selBox[S][0] = jx1; selBox[S][1] = jy1; selBox[S][2] = jx2; selBox[S][3] = jy2;
          selArea[S] = jar; selScore[S] = jsc; selIdx[S] = jidx;
        }
        S++;
        m &= ~(1ULL << j);
        double ltx = fmax(jx1, bx1), lty = fmax(jy1, by1);
        double rbx = fmin(jx2, bx2), rby = fmin(jy2, by2);
        double w = rbx - ltx; w = w < 0 ? 0 : w;
        double h = rby - lty; h = h < 0 ? 0 : h;
        double inter = w * h;
        double denom = jar + area - inter + 1e-9;
        m &= ~__ballot(inter > THR * denom);
      }
      pos += 64;
    }
    if (lane == 0) sS = S;
  }
  __syncthreads();

  const int S = sS;
  float* det_boxes = out;
  float* det_classes = out + Bn * MAXB * 4;
  float* det_scores = out + Bn * MAXB * 4 + Bn * MAXB;
  float* det_num = out + Bn * MAXB * 4 + 2 * Bn * MAXB;
  for (int k = tid; k < MAXB; k += 1024) {
    int o = b * MAXB + k;
    if (k < S) {
      det_boxes[o * 4 + 0] = (float)selBox[k][0];
      det_boxes[o * 4 + 1] = (float)selBox[k][1];
      det_boxes[o * 4 + 2] = (float)selBox[k][2];
      det_boxes[o * 4 + 3] = (float)selBox[k][3];
      det_classes[o] = (float)clsd[b * Nn + selIdx[k]];
      det_scores[o] = selScore[k];
    } else {
      det_boxes[o * 4 + 0] = 0.f; det_boxes[o * 4 + 1] = 0.f;
      det_boxes[o * 4 + 2] = 0.f; det_boxes[o * 4 + 3] = 0.f;
      det_classes[o] = 0.f;
      det_scores[o] = 0.f;
    }
  }
  if (tid == 0) det_num[b] = (float)S;
}

// ============================================================
extern "C" void kernel_launch(void* const* d_in, const int* in_sizes, int n_in,
                              void* d_out, int out_size, void* d_ws, size_t ws_size,
                              hipStream_t stream) {
  const float* logits = (const float*)d_in[0];
  const float* anchors = (const float*)d_in[1];
  float* out = (float*)d_out;
  char* ws = (char*)d_ws;

  // ws: boxesd f64[B*N*4] | clsd i32[B*N] | binA u32[B*N] | hist i32[B*2048]
  //   | Cg i32[B] | cntG i32[B] | clist i32[B*8192] | ekeys u64[B*8192]
  double* boxesd = (double*)ws;
  size_t off = (size_t)Bn * Nn * 4 * sizeof(double);
  int* clsd = (int*)(ws + off);  off += (size_t)Bn * Nn * sizeof(int);
  u32* binA = (u32*)(ws + off);  off += (size_t)Bn * Nn * sizeof(u32);
  int* hist = (int*)(ws + off);  off += (size_t)Bn * NBIN * sizeof(int);
  int* Cg   = (int*)(ws + off);  off += (size_t)Bn * sizeof(int);
  int* cntG = (int*)(ws + off);  off += (size_t)Bn * sizeof(int);
  int* clist= (int*)(ws + off);  off += (size_t)Bn * TSEL * sizeof(int);
  u64* ekeys= (u64*)(ws + off);

  hipMemsetAsync(hist, 0, (size_t)Bn * NBIN * sizeof(int), stream);
  hipMemsetAsync(cntG, 0, (size_t)Bn * sizeof(int), stream);
  k_score  <<<dim3(Bn * 384), dim3(256), 0, stream>>>(logits, binA, hist);
  k_cutoff <<<dim3(Bn),       dim3(256), 0, stream>>>(hist, Cg);
  k_compact<<<dim3(Bn * 96),  dim3(256), 0, stream>>>(binA, Cg, cntG, clist);
  k_rescore<<<dim3(Bn * 64),  dim3(512), 0, stream>>>(logits, anchors, clist, cntG,
                                                      boxesd, clsd, ekeys);
  k_nms    <<<dim3(Bn),       dim3(1024), 0, stream>>>(ekeys, boxesd, clsd, out);
}